// Round 2
// baseline (1030.899 us; speedup 1.0000x reference)
//
#include <hip/hip_runtime.h>

#define DIM 1024
#define SEQ 2048
#define BATCH 2
#define NHEADS 16
#define HD 64
#define ROWS (BATCH * SEQ) // 4096

// ---------------- RMSNorm: one block per row ----------------
__global__ __launch_bounds__(256) void rmsnorm_kernel(const float* __restrict__ x,
                                                      const float* __restrict__ w,
                                                      float* __restrict__ xn) {
    int row = blockIdx.x;
    const float* xr = x + (size_t)row * DIM;
    int t = threadIdx.x;
    float4 v = ((const float4*)xr)[t];
    float ss = v.x * v.x + v.y * v.y + v.z * v.z + v.w * v.w;
#pragma unroll
    for (int off = 1; off < 64; off <<= 1) ss += __shfl_xor(ss, off);
    __shared__ float red[4];
    int lane = t & 63, wv = t >> 6;
    if (lane == 0) red[wv] = ss;
    __syncthreads();
    ss = red[0] + red[1] + red[2] + red[3];
    float scale = rsqrtf(ss * (1.0f / DIM) + 1e-5f);
    float4 wv4 = ((const float4*)w)[t];
    float4 o;
    o.x = v.x * scale * wv4.x;
    o.y = v.y * scale * wv4.y;
    o.z = v.z * scale * wv4.z;
    o.w = v.w * scale * wv4.w;
    ((float4*)(xn + (size_t)row * DIM))[t] = o;
}

// ---------------- fp32 GEMM: C[M,N] = A[M,K] @ B[K,N], 64x64 tile ----------------
__global__ __launch_bounds__(256) void gemm64(const float* __restrict__ A,
                                              const float* __restrict__ Bm,
                                              float* __restrict__ C,
                                              int M, int N, int K) {
    __shared__ float As[16][68]; // k-major, pad 4 -> conflict-light
    __shared__ float Bs[16][64];
    int tid = threadIdx.x;
    int tx = tid & 15, ty = tid >> 4;
    int row0 = blockIdx.y << 6, col0 = blockIdx.x << 6;
    int a_r = tid >> 2, a_c = (tid & 3) << 2;
    int b_r = tid >> 4, b_c = (tid & 15) << 2;
    float acc[4][4] = {};
    for (int k0 = 0; k0 < K; k0 += 16) {
        float4 av = *(const float4*)&A[(size_t)(row0 + a_r) * K + k0 + a_c];
        float4 bv = *(const float4*)&Bm[(size_t)(k0 + b_r) * N + col0 + b_c];
        __syncthreads();
        As[a_c + 0][a_r] = av.x;
        As[a_c + 1][a_r] = av.y;
        As[a_c + 2][a_r] = av.z;
        As[a_c + 3][a_r] = av.w;
        *(float4*)&Bs[b_r][b_c] = bv;
        __syncthreads();
#pragma unroll
        for (int kk = 0; kk < 16; ++kk) {
            float4 a4 = *(const float4*)&As[kk][ty << 2];
            float4 b4 = *(const float4*)&Bs[kk][tx << 2];
            float a[4] = {a4.x, a4.y, a4.z, a4.w};
            float b[4] = {b4.x, b4.y, b4.z, b4.w};
#pragma unroll
            for (int i = 0; i < 4; i++)
#pragma unroll
                for (int j = 0; j < 4; j++) acc[i][j] = fmaf(a[i], b[j], acc[i][j]);
        }
    }
#pragma unroll
    for (int i = 0; i < 4; i++) {
        float4 o = {acc[i][0], acc[i][1], acc[i][2], acc[i][3]};
        *(float4*)&C[(size_t)(row0 + (ty << 2) + i) * N + col0 + (tx << 2)] = o;
    }
}

// ---------------- RoPE table: cos/sin[seq][32] ----------------
__global__ __launch_bounds__(256) void rope_table_kernel(float* __restrict__ cosT,
                                                         float* __restrict__ sinT) {
    int idx = blockIdx.x * 256 + threadIdx.x; // SEQ*32 = 65536
    int s = idx >> 5, i = idx & 31;
    float e = (2.0f * (float)i) / 64.0f;
    float theta = 1.0f / powf(1000000.0f, e);
    float ang = (float)s * theta;
    cosT[idx] = cosf(ang);
    sinT[idx] = sinf(ang);
}

// ---------------- RoPE apply (in-place on q and k) ----------------
__global__ __launch_bounds__(256) void rope_apply_kernel(float* __restrict__ q,
                                                         float* __restrict__ k,
                                                         const float* __restrict__ cosT,
                                                         const float* __restrict__ sinT) {
    int idx = blockIdx.x * 256 + threadIdx.x; // ROWS*512 pairs
    float* t = blockIdx.y ? k : q;
    int row = idx >> 9, p = idx & 511;
    int head = p >> 5, i = p & 31;
    int s = row & (SEQ - 1);
    size_t base = (size_t)row * DIM + head * HD + i;
    float x1 = t[base], x2 = t[base + 32];
    float c = cosT[s * 32 + i], sn = sinT[s * 32 + i];
    t[base] = x1 * c - x2 * sn;
    t[base + 32] = x1 * sn + x2 * c;
}

// ---------------- Causal flash attention, fp32, 64-row q-tile ----------------
__global__ __launch_bounds__(256) void attn_kernel(const float* __restrict__ q,
                                                   const float* __restrict__ k,
                                                   const float* __restrict__ v,
                                                   float* __restrict__ ctx) {
    int qt = blockIdx.x, bh = blockIdx.y;
    int b = bh >> 4, h = bh & 15;
    int q0 = qt << 6;
    __shared__ float Qs[64][68];
    __shared__ float KtPs[64][68]; // K^T during S phase, P during PV phase (aliased)
    __shared__ float Vs[64][64];
    int tid = threadIdx.x;
    int tx = tid & 15, ty = tid >> 4;
    int lr = tid >> 2, lc = (tid & 3) << 2;
    const size_t hoff = (size_t)b * SEQ * DIM + (size_t)h * HD;

    // Full 64x64 Q tile: each thread loads 4 float4 chunks (cols lc+{0,16,32,48})
#pragma unroll
    for (int c = 0; c < 64; c += 16) {
        float4 qv = *(const float4*)&q[hoff + (size_t)(q0 + lr) * DIM + lc + c];
        *(float4*)&Qs[lr][lc + c] = qv;
    }

    float acc[4][4] = {};
    float m_run[4], l_run[4];
#pragma unroll
    for (int i = 0; i < 4; i++) {
        m_run[i] = -1e30f;
        l_run[i] = 0.f;
    }

    for (int st = 0; st <= qt; ++st) {
        int s0 = st << 6;
        float4 kv[4], vv[4];
#pragma unroll
        for (int c = 0; c < 4; c++) {
            kv[c] = *(const float4*)&k[hoff + (size_t)(s0 + lr) * DIM + lc + 16 * c];
            vv[c] = *(const float4*)&v[hoff + (size_t)(s0 + lr) * DIM + lc + 16 * c];
        }
        __syncthreads(); // prev PV done (and Qs visible on first iter)
#pragma unroll
        for (int c = 0; c < 4; c++) {
            KtPs[lc + 16 * c + 0][lr] = kv[c].x;
            KtPs[lc + 16 * c + 1][lr] = kv[c].y;
            KtPs[lc + 16 * c + 2][lr] = kv[c].z;
            KtPs[lc + 16 * c + 3][lr] = kv[c].w;
            *(float4*)&Vs[lr][lc + 16 * c] = vv[c];
        }
        __syncthreads();

        // S = Q @ K^T (4x4 per thread)
        float sv[4][4] = {};
#pragma unroll
        for (int d0 = 0; d0 < 64; d0 += 4) {
            float4 a4[4], b4[4];
#pragma unroll
            for (int i = 0; i < 4; i++) a4[i] = *(const float4*)&Qs[(ty << 2) + i][d0];
#pragma unroll
            for (int u = 0; u < 4; u++) b4[u] = *(const float4*)&KtPs[d0 + u][tx << 2];
#pragma unroll
            for (int i = 0; i < 4; i++) {
                float ax[4] = {a4[i].x, a4[i].y, a4[i].z, a4[i].w};
#pragma unroll
                for (int u = 0; u < 4; u++) {
                    float bx[4] = {b4[u].x, b4[u].y, b4[u].z, b4[u].w};
#pragma unroll
                    for (int j = 0; j < 4; j++) sv[i][j] = fmaf(ax[u], bx[j], sv[i][j]);
                }
            }
        }
        __syncthreads(); // S reads of K^T done before P overwrites the buffer

        bool diag = (st == qt);
#pragma unroll
        for (int i = 0; i < 4; i++) {
#pragma unroll
            for (int j = 0; j < 4; j++) {
                float val = sv[i][j] * 0.125f;
                if (diag && (s0 + (tx << 2) + j) > (q0 + (ty << 2) + i)) val = -1e30f;
                sv[i][j] = val;
            }
        }

        // online softmax per row (row spread over 16 tx lanes)
#pragma unroll
        for (int i = 0; i < 4; i++) {
            float mt = fmaxf(fmaxf(sv[i][0], sv[i][1]), fmaxf(sv[i][2], sv[i][3]));
#pragma unroll
            for (int off = 1; off < 16; off <<= 1) mt = fmaxf(mt, __shfl_xor(mt, off));
            float m_new = fmaxf(m_run[i], mt);
            float alpha = __expf(m_run[i] - m_new);
            float p[4];
            float ps = 0.f;
#pragma unroll
            for (int j = 0; j < 4; j++) {
                p[j] = __expf(sv[i][j] - m_new);
                ps += p[j];
            }
#pragma unroll
            for (int off = 1; off < 16; off <<= 1) ps += __shfl_xor(ps, off);
            l_run[i] = l_run[i] * alpha + ps;
            m_run[i] = m_new;
#pragma unroll
            for (int j = 0; j < 4; j++) acc[i][j] *= alpha;
            float4 pp = {p[0], p[1], p[2], p[3]};
            *(float4*)&KtPs[(ty << 2) + i][tx << 2] = pp; // P tile
        }
        __syncthreads();

        // acc += P @ V
#pragma unroll
        for (int s4 = 0; s4 < 64; s4 += 4) {
            float4 p4[4], v4[4];
#pragma unroll
            for (int i = 0; i < 4; i++) p4[i] = *(const float4*)&KtPs[(ty << 2) + i][s4];
#pragma unroll
            for (int u = 0; u < 4; u++) v4[u] = *(const float4*)&Vs[s4 + u][tx << 2];
#pragma unroll
            for (int i = 0; i < 4; i++) {
                float px[4] = {p4[i].x, p4[i].y, p4[i].z, p4[i].w};
#pragma unroll
                for (int u = 0; u < 4; u++) {
                    float vx[4] = {v4[u].x, v4[u].y, v4[u].z, v4[u].w};
#pragma unroll
                    for (int j = 0; j < 4; j++) acc[i][j] = fmaf(px[u], vx[j], acc[i][j]);
                }
            }
        }
    }

#pragma unroll
    for (int i = 0; i < 4; i++) {
        float invl = 1.0f / l_run[i];
        float4 o = {acc[i][0] * invl, acc[i][1] * invl, acc[i][2] * invl, acc[i][3] * invl};
        *(float4*)&ctx[hoff + (size_t)(q0 + (ty << 2) + i) * DIM + (tx << 2)] = o;
    }
}

extern "C" void kernel_launch(void* const* d_in, const int* in_sizes, int n_in,
                              void* d_out, int out_size, void* d_ws, size_t ws_size,
                              hipStream_t stream) {
    const float* x = (const float*)d_in[0];
    const float* w_norm = (const float*)d_in[1];
    const float* Wq = (const float*)d_in[2];
    const float* Wk = (const float*)d_in[3];
    const float* Wv = (const float*)d_in[4];
    const float* Wo = (const float*)d_in[5];
    float* out = (float*)d_out;
    float* ws = (float*)d_ws;

    const size_t NM = (size_t)ROWS * DIM; // 4,194,304 floats
    float* qb = ws;
    float* kb = ws + NM;
    float* vb = ws + 2 * NM;
    float* xn = ws + 3 * NM; // reused as ctx after QKV
    float* cosT = ws + 4 * NM;
    float* sinT = cosT + SEQ * 32;

    rmsnorm_kernel<<<ROWS, 256, 0, stream>>>(x, w_norm, xn);
    rope_table_kernel<<<(SEQ * 32) / 256, 256, 0, stream>>>(cosT, sinT);

    dim3 ggrid(DIM / 64, ROWS / 64);
    gemm64<<<ggrid, 256, 0, stream>>>(xn, Wq, qb, ROWS, DIM, DIM);
    gemm64<<<ggrid, 256, 0, stream>>>(xn, Wk, kb, ROWS, DIM, DIM);
    gemm64<<<ggrid, 256, 0, stream>>>(xn, Wv, vb, ROWS, DIM, DIM);

    rope_apply_kernel<<<dim3((ROWS * 512) / 256, 2), 256, 0, stream>>>(qb, kb, cosT, sinT);

    float* ctx = xn;
    attn_kernel<<<dim3(SEQ / 64, BATCH * NHEADS), 256, 0, stream>>>(qb, kb, vb, ctx);

    gemm64<<<ggrid, 256, 0, stream>>>(ctx, Wo, out, ROWS, DIM, DIM);
}

// Round 3
// 158.598 us; speedup vs baseline: 6.5001x; 6.5001x over previous
//
#include <hip/hip_runtime.h>

#define DIM 1024
#define SEQ 2048
#define BATCH 2
#define NHEADS 16
#define HD 64
#define ROWS (BATCH * SEQ) // 4096

typedef __bf16 bf16x8 __attribute__((ext_vector_type(8)));
typedef __bf16 bf16x4 __attribute__((ext_vector_type(4)));
typedef float f32x4 __attribute__((ext_vector_type(4)));

__device__ __forceinline__ f32x4 f4zero() {
    f32x4 z = {0.f, 0.f, 0.f, 0.f};
    return z;
}

// ---------------- RMSNorm -> bf16 ----------------
__global__ __launch_bounds__(256) void rmsnorm_bf16(const float* __restrict__ x,
                                                    const float* __restrict__ w,
                                                    __bf16* __restrict__ xn) {
    int row = blockIdx.x;
    int t = threadIdx.x;
    float4 v = ((const float4*)(x + (size_t)row * DIM))[t];
    float ss = v.x * v.x + v.y * v.y + v.z * v.z + v.w * v.w;
#pragma unroll
    for (int off = 1; off < 64; off <<= 1) ss += __shfl_xor(ss, off);
    __shared__ float red[4];
    if ((t & 63) == 0) red[t >> 6] = ss;
    __syncthreads();
    ss = red[0] + red[1] + red[2] + red[3];
    float scale = rsqrtf(ss * (1.0f / DIM) + 1e-5f);
    float4 wv = ((const float4*)w)[t];
    bf16x4 o;
    o[0] = (__bf16)(v.x * scale * wv.x);
    o[1] = (__bf16)(v.y * scale * wv.y);
    o[2] = (__bf16)(v.z * scale * wv.z);
    o[3] = (__bf16)(v.w * scale * wv.w);
    *(bf16x4*)(xn + (size_t)row * DIM + t * 4) = o;
}

// ---------------- Weight convert + transpose: W[k][n] f32 -> Wt[n][k] bf16 ----------------
__global__ __launch_bounds__(256) void wcvt_kernel(const float* __restrict__ Wq,
                                                   const float* __restrict__ Wk,
                                                   const float* __restrict__ Wv,
                                                   const float* __restrict__ Wo,
                                                   __bf16* tq, __bf16* tk, __bf16* tv, __bf16* to_) {
    int z = blockIdx.z;
    const float* W = z == 0 ? Wq : z == 1 ? Wk : z == 2 ? Wv : Wo;
    __bf16* T = z == 0 ? tq : z == 1 ? tk : z == 2 ? tv : to_;
    __shared__ float tile[32][33];
    int n0 = blockIdx.x * 32, k0 = blockIdx.y * 32;
    int tx = threadIdx.x & 31, ty = threadIdx.x >> 5;
#pragma unroll
    for (int j = 0; j < 32; j += 8) tile[ty + j][tx] = W[(size_t)(k0 + ty + j) * DIM + n0 + tx];
    __syncthreads();
#pragma unroll
    for (int j = 0; j < 32; j += 8)
        T[(size_t)(n0 + ty + j) * DIM + k0 + tx] = (__bf16)tile[tx][ty + j];
}

// ---------------- RoPE table ----------------
__global__ __launch_bounds__(256) void rope_table_kernel(float* __restrict__ cosT,
                                                         float* __restrict__ sinT) {
    int idx = blockIdx.x * 256 + threadIdx.x; // SEQ*32
    int s = idx >> 5, i = idx & 31;
    float e = (2.0f * (float)i) / 64.0f;
    float theta = 1.0f / powf(1000000.0f, e);
    float ang = (float)s * theta;
    cosT[idx] = cosf(ang);
    sinT[idx] = sinf(ang);
}

// ---------------- RoPE apply on bf16 q/k ----------------
__global__ __launch_bounds__(256) void rope_apply_bf16(__bf16* __restrict__ q,
                                                       __bf16* __restrict__ k,
                                                       const float* __restrict__ cosT,
                                                       const float* __restrict__ sinT) {
    int idx = blockIdx.x * 256 + threadIdx.x; // ROWS*16heads*4chunks = 262144
    __bf16* t = blockIdx.y ? k : q;
    int row = idx >> 6, rem = idx & 63;
    int head = rem >> 2, i0 = (rem & 3) * 8;
    int s = row & (SEQ - 1);
    size_t base = (size_t)row * DIM + head * HD + i0;
    bf16x8 x1 = *(const bf16x8*)&t[base];
    bf16x8 x2 = *(const bf16x8*)&t[base + 32];
    const float* cp = cosT + s * 32 + i0;
    const float* sp = sinT + s * 32 + i0;
    bf16x8 y1, y2;
#pragma unroll
    for (int j = 0; j < 8; ++j) {
        float a = (float)x1[j], b = (float)x2[j];
        float c = cp[j], sn = sp[j];
        y1[j] = (__bf16)(a * c - b * sn);
        y2[j] = (__bf16)(a * sn + b * c);
    }
    *(bf16x8*)&t[base] = y1;
    *(bf16x8*)&t[base + 32] = y2;
}

// ---------------- V transpose: v[b*S+s][h*64+d] -> vt[bh][d][s] ----------------
__global__ __launch_bounds__(256) void vtrans_kernel(const __bf16* __restrict__ v,
                                                     __bf16* __restrict__ vt) {
    __shared__ __bf16 tile[32][33];
    int bh = blockIdx.z;
    int b = bh >> 4, h = bh & 15;
    int s0 = blockIdx.x * 32, d0 = blockIdx.y * 32;
    int tx = threadIdx.x & 31, ty = threadIdx.x >> 5;
    const __bf16* src = v + (size_t)(b * SEQ) * DIM + h * HD;
#pragma unroll
    for (int j = 0; j < 32; j += 8) tile[ty + j][tx] = src[(size_t)(s0 + ty + j) * DIM + d0 + tx];
    __syncthreads();
    __bf16* dst = vt + ((size_t)bh * HD + d0) * SEQ + s0;
#pragma unroll
    for (int j = 0; j < 32; j += 8) dst[(size_t)(ty + j) * SEQ + tx] = tile[tx][ty + j];
}

// ---------------- MFMA GEMM body: C[M,N] = A[M,K]bf16 @ Wt[N,K]bf16 ----------------
template <typename OutT>
__device__ __forceinline__ void gemm_body(const __bf16* __restrict__ A,
                                          const __bf16* __restrict__ Bt,
                                          OutT* __restrict__ C,
                                          int K, int N, int row0, int col0) {
    __shared__ __bf16 As[128][56]; // stride 112B: 16B-aligned rows, conflict-light
    __shared__ __bf16 Bs[128][56];
    int tid = threadIdx.x;
    int w = tid >> 6, l = tid & 63, l15 = l & 15, g = l >> 4;
    int wr = (w >> 1) << 6, wc = (w & 1) << 6;
    int c0 = tid, c1 = tid + 256;
    int r0 = c0 >> 2, o0 = (c0 & 3) * 8;
    int r1 = c1 >> 2, o1 = (c1 & 3) * 8;

    f32x4 acc[4][4];
#pragma unroll
    for (int i = 0; i < 4; ++i)
#pragma unroll
        for (int j = 0; j < 4; ++j) acc[i][j] = f4zero();

    bf16x8 ra[2], rb[2];
    ra[0] = *(const bf16x8*)&A[(size_t)(row0 + r0) * K + o0];
    ra[1] = *(const bf16x8*)&A[(size_t)(row0 + r1) * K + o1];
    rb[0] = *(const bf16x8*)&Bt[(size_t)(col0 + r0) * K + o0];
    rb[1] = *(const bf16x8*)&Bt[(size_t)(col0 + r1) * K + o1];

    for (int k0 = 0; k0 < K; k0 += 32) {
        __syncthreads();
        *(bf16x8*)&As[r0][o0] = ra[0];
        *(bf16x8*)&As[r1][o1] = ra[1];
        *(bf16x8*)&Bs[r0][o0] = rb[0];
        *(bf16x8*)&Bs[r1][o1] = rb[1];
        __syncthreads();
        if (k0 + 32 < K) {
            int kn = k0 + 32;
            ra[0] = *(const bf16x8*)&A[(size_t)(row0 + r0) * K + kn + o0];
            ra[1] = *(const bf16x8*)&A[(size_t)(row0 + r1) * K + kn + o1];
            rb[0] = *(const bf16x8*)&Bt[(size_t)(col0 + r0) * K + kn + o0];
            rb[1] = *(const bf16x8*)&Bt[(size_t)(col0 + r1) * K + kn + o1];
        }
        bf16x8 af[4], bfr[4];
#pragma unroll
        for (int i = 0; i < 4; ++i) af[i] = *(const bf16x8*)&As[wr + i * 16 + l15][g * 8];
#pragma unroll
        for (int j = 0; j < 4; ++j) bfr[j] = *(const bf16x8*)&Bs[wc + j * 16 + l15][g * 8];
#pragma unroll
        for (int i = 0; i < 4; ++i)
#pragma unroll
            for (int j = 0; j < 4; ++j)
                acc[i][j] = __builtin_amdgcn_mfma_f32_16x16x32_bf16(af[i], bfr[j], acc[i][j], 0, 0, 0);
    }
#pragma unroll
    for (int i = 0; i < 4; ++i)
#pragma unroll
        for (int j = 0; j < 4; ++j)
#pragma unroll
            for (int r = 0; r < 4; ++r) {
                int row = row0 + wr + i * 16 + g * 4 + r;
                int col = col0 + wc + j * 16 + l15;
                C[(size_t)row * N + col] = (OutT)acc[i][j][r];
            }
}

__global__ __launch_bounds__(256) void gemm_qkv_kernel(const __bf16* __restrict__ xn,
                                                       const __bf16* __restrict__ wq,
                                                       const __bf16* __restrict__ wk,
                                                       const __bf16* __restrict__ wv,
                                                       __bf16* q, __bf16* k, __bf16* v) {
    int z = blockIdx.z;
    const __bf16* Bt = z == 0 ? wq : z == 1 ? wk : wv;
    __bf16* C = z == 0 ? q : z == 1 ? k : v;
    gemm_body<__bf16>(xn, Bt, C, DIM, DIM, (int)blockIdx.y << 7, (int)blockIdx.x << 7);
}

__global__ __launch_bounds__(256) void gemm_out_kernel(const __bf16* __restrict__ ctx,
                                                       const __bf16* __restrict__ wo,
                                                       float* __restrict__ out) {
    gemm_body<float>(ctx, wo, out, DIM, DIM, (int)blockIdx.y << 7, (int)blockIdx.x << 7);
}

// ---------------- MFMA causal flash attention ----------------
// 4 waves/block; wave w owns q-rows [q0+16w, q0+16w+16); K tile + V^T tile in LDS.
__global__ __launch_bounds__(256) void attn_mfma_kernel(const __bf16* __restrict__ q,
                                                        const __bf16* __restrict__ k,
                                                        const __bf16* __restrict__ vt,
                                                        __bf16* __restrict__ ctx) {
    int bh = blockIdx.x;
    int qt = 31 - (int)blockIdx.y; // heavy tiles dispatch first
    int b = bh >> 4, h = bh & 15;
    int q0 = qt << 6;
    __shared__ __bf16 Ks[64][72]; // [s][d], 144B rows: aligned + conflict-free
    __shared__ __bf16 Vl[64][72]; // [d][s_local]
    __shared__ __bf16 Ps[4][16][72];
    int tid = threadIdx.x, w = tid >> 6, l = tid & 63, l15 = l & 15, g = l >> 4;
    size_t hoff = (size_t)(b * SEQ) * DIM + h * HD;
    const __bf16* vth = vt + (size_t)bh * HD * SEQ;

    // Q fragments in registers for the whole block-row
    bf16x8 aq[2];
    {
        int qrow = q0 + w * 16 + l15;
        aq[0] = *(const bf16x8*)&q[hoff + (size_t)qrow * DIM + g * 8];
        aq[1] = *(const bf16x8*)&q[hoff + (size_t)qrow * DIM + 32 + g * 8];
    }

    f32x4 acc_o[4];
#pragma unroll
    for (int j = 0; j < 4; ++j) acc_o[j] = f4zero();
    float m_run[4], l_run[4];
#pragma unroll
    for (int r = 0; r < 4; ++r) {
        m_run[r] = -1e30f;
        l_run[r] = 0.f;
    }

    int c0 = tid, c1 = tid + 256;
    int kr0 = c0 >> 3, ko0 = (c0 & 7) * 8;
    int kr1 = c1 >> 3, ko1 = (c1 & 7) * 8;
    bf16x8 rk[2], rv[2];
    rk[0] = *(const bf16x8*)&k[hoff + (size_t)kr0 * DIM + ko0];
    rk[1] = *(const bf16x8*)&k[hoff + (size_t)kr1 * DIM + ko1];
    rv[0] = *(const bf16x8*)&vth[(size_t)kr0 * SEQ + ko0];
    rv[1] = *(const bf16x8*)&vth[(size_t)kr1 * SEQ + ko1];

    for (int st = 0; st <= qt; ++st) {
        int s0 = st << 6;
        __syncthreads(); // previous tile's LDS reads done
        *(bf16x8*)&Ks[kr0][ko0] = rk[0];
        *(bf16x8*)&Ks[kr1][ko1] = rk[1];
        *(bf16x8*)&Vl[kr0][ko0] = rv[0];
        *(bf16x8*)&Vl[kr1][ko1] = rv[1];
        __syncthreads();
        if (st < qt) { // prefetch next tile
            int sn = s0 + 64;
            rk[0] = *(const bf16x8*)&k[hoff + (size_t)(sn + kr0) * DIM + ko0];
            rk[1] = *(const bf16x8*)&k[hoff + (size_t)(sn + kr1) * DIM + ko1];
            rv[0] = *(const bf16x8*)&vth[(size_t)kr0 * SEQ + sn + ko0];
            rv[1] = *(const bf16x8*)&vth[(size_t)kr1 * SEQ + sn + ko1];
        }

        // S = Q @ K^T  (wave: 16 rows x 64 cols)
        f32x4 sacc[4];
#pragma unroll
        for (int j = 0; j < 4; ++j) sacc[j] = f4zero();
#pragma unroll
        for (int j = 0; j < 4; ++j) {
            bf16x8 bk0 = *(const bf16x8*)&Ks[j * 16 + l15][g * 8];
            bf16x8 bk1 = *(const bf16x8*)&Ks[j * 16 + l15][32 + g * 8];
            sacc[j] = __builtin_amdgcn_mfma_f32_16x16x32_bf16(aq[0], bk0, sacc[j], 0, 0, 0);
            sacc[j] = __builtin_amdgcn_mfma_f32_16x16x32_bf16(aq[1], bk1, sacc[j], 0, 0, 0);
        }

        bool diag = (st == qt);
        // online softmax; lane holds rows g*4+r, cols j*16+l15
#pragma unroll
        for (int r = 0; r < 4; ++r) {
            int rowq = q0 + w * 16 + g * 4 + r;
            float mt = -3e38f;
#pragma unroll
            for (int j = 0; j < 4; ++j) {
                float vsc = sacc[j][r] * 0.125f;
                if (diag && (s0 + j * 16 + l15) > rowq) vsc = -1e30f;
                sacc[j][r] = vsc;
                mt = fmaxf(mt, vsc);
            }
#pragma unroll
            for (int off = 1; off < 16; off <<= 1) mt = fmaxf(mt, __shfl_xor(mt, off));
            float m_new = fmaxf(m_run[r], mt);
            float alpha = __expf(m_run[r] - m_new);
            float rs = 0.f;
#pragma unroll
            for (int j = 0; j < 4; ++j) {
                float p = __expf(sacc[j][r] - m_new);
                sacc[j][r] = p;
                rs += p;
            }
#pragma unroll
            for (int off = 1; off < 16; off <<= 1) rs += __shfl_xor(rs, off);
            l_run[r] = l_run[r] * alpha + rs;
            m_run[r] = m_new;
#pragma unroll
            for (int j = 0; j < 4; ++j) acc_o[j][r] *= alpha;
        }

        // P -> LDS (per-wave buffer; in-wave DS ordering, no barrier needed)
#pragma unroll
        for (int r = 0; r < 4; ++r)
#pragma unroll
            for (int j = 0; j < 4; ++j) Ps[w][g * 4 + r][j * 16 + l15] = (__bf16)sacc[j][r];

        bf16x8 ap0 = *(const bf16x8*)&Ps[w][l15][g * 8];
        bf16x8 ap1 = *(const bf16x8*)&Ps[w][l15][32 + g * 8];
#pragma unroll
        for (int jd = 0; jd < 4; ++jd) {
            bf16x8 bv0 = *(const bf16x8*)&Vl[jd * 16 + l15][g * 8];
            bf16x8 bv1 = *(const bf16x8*)&Vl[jd * 16 + l15][32 + g * 8];
            acc_o[jd] = __builtin_amdgcn_mfma_f32_16x16x32_bf16(ap0, bv0, acc_o[jd], 0, 0, 0);
            acc_o[jd] = __builtin_amdgcn_mfma_f32_16x16x32_bf16(ap1, bv1, acc_o[jd], 0, 0, 0);
        }
    }

#pragma unroll
    for (int r = 0; r < 4; ++r) {
        float inv = 1.0f / l_run[r];
        int row = q0 + w * 16 + g * 4 + r;
#pragma unroll
        for (int jd = 0; jd < 4; ++jd)
            ctx[hoff + (size_t)row * DIM + jd * 16 + l15] = (__bf16)(acc_o[jd][r] * inv);
    }
}

extern "C" void kernel_launch(void* const* d_in, const int* in_sizes, int n_in,
                              void* d_out, int out_size, void* d_ws, size_t ws_size,
                              hipStream_t stream) {
    const float* x = (const float*)d_in[0];
    const float* w_norm = (const float*)d_in[1];
    const float* Wq = (const float*)d_in[2];
    const float* Wk = (const float*)d_in[3];
    const float* Wv = (const float*)d_in[4];
    const float* Wo = (const float*)d_in[5];
    float* out = (float*)d_out;
    char* w8 = (char*)d_ws;

    __bf16* xn = (__bf16*)(w8);                      // 8 MB
    __bf16* wtq = (__bf16*)(w8 + (8ull << 20));      // 2 MB each
    __bf16* wtk = (__bf16*)(w8 + (10ull << 20));
    __bf16* wtv = (__bf16*)(w8 + (12ull << 20));
    __bf16* wto = (__bf16*)(w8 + (14ull << 20));
    __bf16* qb = (__bf16*)(w8 + (16ull << 20));      // 8 MB each
    __bf16* kb = (__bf16*)(w8 + (24ull << 20));
    __bf16* vb = (__bf16*)(w8 + (32ull << 20));
    __bf16* vtb = (__bf16*)(w8 + (40ull << 20));
    __bf16* ctx = (__bf16*)(w8 + (48ull << 20));
    float* cosT = (float*)(w8 + (56ull << 20));
    float* sinT = cosT + SEQ * 32;

    wcvt_kernel<<<dim3(32, 32, 4), 256, 0, stream>>>(Wq, Wk, Wv, Wo, wtq, wtk, wtv, wto);
    rmsnorm_bf16<<<ROWS, 256, 0, stream>>>(x, w_norm, xn);
    rope_table_kernel<<<(SEQ * 32) / 256, 256, 0, stream>>>(cosT, sinT);

    gemm_qkv_kernel<<<dim3(DIM / 128, ROWS / 128, 3), 256, 0, stream>>>(xn, wtq, wtk, wtv, qb, kb, vb);

    rope_apply_bf16<<<dim3((ROWS * 64) / 256, 2), 256, 0, stream>>>(qb, kb, cosT, sinT);
    vtrans_kernel<<<dim3(SEQ / 32, HD / 32, BATCH * NHEADS), 256, 0, stream>>>(vb, vtb);

    attn_mfma_kernel<<<dim3(BATCH * NHEADS, SEQ / 64), 256, 0, stream>>>(qb, kb, vtb, ctx);

    gemm_out_kernel<<<dim3(DIM / 128, ROWS / 128), 256, 0, stream>>>(ctx, wto, out);
}

// Round 4
// 149.532 us; speedup vs baseline: 6.8942x; 1.0606x over previous
//
#include <hip/hip_runtime.h>

#define DIM 1024
#define SEQ 2048
#define BATCH 2
#define NHEADS 16
#define HD 64
#define ROWS (BATCH * SEQ) // 4096

typedef __bf16 bf16x8 __attribute__((ext_vector_type(8)));
typedef __bf16 bf16x4 __attribute__((ext_vector_type(4)));
typedef float f32x4 __attribute__((ext_vector_type(4)));

__device__ __forceinline__ f32x4 f4zero() {
    f32x4 z = {0.f, 0.f, 0.f, 0.f};
    return z;
}

#define GLOAD_LDS16(g, l)                                                                  \
    __builtin_amdgcn_global_load_lds((const __attribute__((address_space(1))) void*)(g),   \
                                     (__attribute__((address_space(3))) void*)(l), 16, 0, 0)

// ---------------- RMSNorm -> bf16 ----------------
__global__ __launch_bounds__(256) void rmsnorm_bf16(const float* __restrict__ x,
                                                    const float* __restrict__ w,
                                                    __bf16* __restrict__ xn) {
    int row = blockIdx.x;
    int t = threadIdx.x;
    float4 v = ((const float4*)(x + (size_t)row * DIM))[t];
    float ss = v.x * v.x + v.y * v.y + v.z * v.z + v.w * v.w;
#pragma unroll
    for (int off = 1; off < 64; off <<= 1) ss += __shfl_xor(ss, off);
    __shared__ float red[4];
    if ((t & 63) == 0) red[t >> 6] = ss;
    __syncthreads();
    ss = red[0] + red[1] + red[2] + red[3];
    float scale = rsqrtf(ss * (1.0f / DIM) + 1e-5f);
    float4 wv = ((const float4*)w)[t];
    bf16x4 o;
    o[0] = (__bf16)(v.x * scale * wv.x);
    o[1] = (__bf16)(v.y * scale * wv.y);
    o[2] = (__bf16)(v.z * scale * wv.z);
    o[3] = (__bf16)(v.w * scale * wv.w);
    *(bf16x4*)(xn + (size_t)row * DIM + t * 4) = o;
}

// ---------------- Weight convert + transpose: W[k][n] f32 -> Wt[n][k] bf16 ----------------
__global__ __launch_bounds__(256) void wcvt_kernel(const float* __restrict__ Wq,
                                                   const float* __restrict__ Wk,
                                                   const float* __restrict__ Wv,
                                                   const float* __restrict__ Wo,
                                                   __bf16* tq, __bf16* tk, __bf16* tv, __bf16* to_) {
    int z = blockIdx.z;
    const float* W = z == 0 ? Wq : z == 1 ? Wk : z == 2 ? Wv : Wo;
    __bf16* T = z == 0 ? tq : z == 1 ? tk : z == 2 ? tv : to_;
    __shared__ float tile[32][33];
    int n0 = blockIdx.x * 32, k0 = blockIdx.y * 32;
    int tx = threadIdx.x & 31, ty = threadIdx.x >> 5;
#pragma unroll
    for (int j = 0; j < 32; j += 8) tile[ty + j][tx] = W[(size_t)(k0 + ty + j) * DIM + n0 + tx];
    __syncthreads();
#pragma unroll
    for (int j = 0; j < 32; j += 8)
        T[(size_t)(n0 + ty + j) * DIM + k0 + tx] = (__bf16)tile[tx][ty + j];
}

// ---------------- RoPE table ----------------
__global__ __launch_bounds__(256) void rope_table_kernel(float* __restrict__ cosT,
                                                         float* __restrict__ sinT) {
    int idx = blockIdx.x * 256 + threadIdx.x; // SEQ*32
    int s = idx >> 5, i = idx & 31;
    float e = (2.0f * (float)i) / 64.0f;
    float theta = 1.0f / powf(1000000.0f, e);
    float ang = (float)s * theta;
    cosT[idx] = cosf(ang);
    sinT[idx] = sinf(ang);
}

// ---------------- RoPE apply on bf16 q/k ----------------
__global__ __launch_bounds__(256) void rope_apply_bf16(__bf16* __restrict__ q,
                                                       __bf16* __restrict__ k,
                                                       const float* __restrict__ cosT,
                                                       const float* __restrict__ sinT) {
    int idx = blockIdx.x * 256 + threadIdx.x;
    __bf16* t = blockIdx.y ? k : q;
    int row = idx >> 6, rem = idx & 63;
    int head = rem >> 2, i0 = (rem & 3) * 8;
    int s = row & (SEQ - 1);
    size_t base = (size_t)row * DIM + head * HD + i0;
    bf16x8 x1 = *(const bf16x8*)&t[base];
    bf16x8 x2 = *(const bf16x8*)&t[base + 32];
    const float* cp = cosT + s * 32 + i0;
    const float* sp = sinT + s * 32 + i0;
    bf16x8 y1, y2;
#pragma unroll
    for (int j = 0; j < 8; ++j) {
        float a = (float)x1[j], b = (float)x2[j];
        float c = cp[j], sn = sp[j];
        y1[j] = (__bf16)(a * c - b * sn);
        y2[j] = (__bf16)(a * sn + b * c);
    }
    *(bf16x8*)&t[base] = y1;
    *(bf16x8*)&t[base + 32] = y2;
}

// ---------------- V transpose: v[b*S+s][h*64+d] -> vt[bh][d][s] ----------------
__global__ __launch_bounds__(256) void vtrans_kernel(const __bf16* __restrict__ v,
                                                     __bf16* __restrict__ vt) {
    __shared__ __bf16 tile[32][33];
    int bh = blockIdx.z;
    int b = bh >> 4, h = bh & 15;
    int s0 = blockIdx.x * 32, d0 = blockIdx.y * 32;
    int tx = threadIdx.x & 31, ty = threadIdx.x >> 5;
    const __bf16* src = v + (size_t)(b * SEQ) * DIM + h * HD;
#pragma unroll
    for (int j = 0; j < 32; j += 8) tile[ty + j][tx] = src[(size_t)(s0 + ty + j) * DIM + d0 + tx];
    __syncthreads();
    __bf16* dst = vt + ((size_t)bh * HD + d0) * SEQ + s0;
#pragma unroll
    for (int j = 0; j < 32; j += 8) dst[(size_t)(ty + j) * SEQ + tx] = tile[tx][ty + j];
}

// ---------------- MFMA GEMM (m97-style): C[M,N]=A[M,K]bf16 @ Wt[N,K]bf16 ----------------
// 128x128 tile, BK=32, global_load_lds w16 into linear LDS with chunk-XOR swizzle
// (chunk ^= (row>>1)&3) applied on BOTH global source and ds_read addresses (G21).
template <typename OutT>
__device__ __forceinline__ void gemm_body(const __bf16* __restrict__ A,
                                          const __bf16* __restrict__ Bt,
                                          OutT* __restrict__ C,
                                          int K, int N, int row0, int col0) {
    __shared__ __bf16 As[128 * 32];
    __shared__ __bf16 Bs[128 * 32];
    int tid = threadIdx.x;
    int w = tid >> 6, l = tid & 63, l15 = l & 15, g = l >> 4;
    int wr = (w >> 1) << 6, wc = (w & 1) << 6;

    // staging: issue i covers LDS elems i*2048 + tid*8 .. +8
    int sr0 = tid >> 2;                                // rows 0..63
    int sr1 = 64 + (tid >> 2);                         // rows 64..127
    int lc0 = (((tid & 3) ^ ((tid >> 3) & 3)) << 3);   // swizzled logical col chunk
    const __bf16* gA0 = A + (size_t)(row0 + sr0) * K + lc0;
    const __bf16* gA1 = A + (size_t)(row0 + sr1) * K + lc0;
    const __bf16* gB0 = Bt + (size_t)(col0 + sr0) * K + lc0;
    const __bf16* gB1 = Bt + (size_t)(col0 + sr1) * K + lc0;
    __bf16* lA0 = As + w * 512;
    __bf16* lA1 = As + 2048 + w * 512;
    __bf16* lB0 = Bs + w * 512;
    __bf16* lB1 = Bs + 2048 + w * 512;

    // frag-read swizzled chunk offsets (row = ..+l15 -> s = (l15>>1)&3, same for all i)
    int rca = ((g ^ ((l15 >> 1) & 3)) << 3);

    f32x4 acc[4][4];
#pragma unroll
    for (int i = 0; i < 4; ++i)
#pragma unroll
        for (int j = 0; j < 4; ++j) acc[i][j] = f4zero();

    for (int k0 = 0; k0 < K; k0 += 32) {
        __syncthreads(); // previous tile's frag reads done
        GLOAD_LDS16(gA0 + k0, lA0);
        GLOAD_LDS16(gA1 + k0, lA1);
        GLOAD_LDS16(gB0 + k0, lB0);
        GLOAD_LDS16(gB1 + k0, lB1);
        __syncthreads(); // drains vmcnt(0): LDS tile ready

        bf16x8 af[4], bfr[4];
#pragma unroll
        for (int i = 0; i < 4; ++i) af[i] = *(const bf16x8*)&As[(wr + i * 16 + l15) * 32 + rca];
#pragma unroll
        for (int j = 0; j < 4; ++j) bfr[j] = *(const bf16x8*)&Bs[(wc + j * 16 + l15) * 32 + rca];
        __builtin_amdgcn_s_setprio(1);
#pragma unroll
        for (int i = 0; i < 4; ++i)
#pragma unroll
            for (int j = 0; j < 4; ++j)
                acc[i][j] = __builtin_amdgcn_mfma_f32_16x16x32_bf16(af[i], bfr[j], acc[i][j], 0, 0, 0);
        __builtin_amdgcn_s_setprio(0);
    }
#pragma unroll
    for (int i = 0; i < 4; ++i)
#pragma unroll
        for (int j = 0; j < 4; ++j)
#pragma unroll
            for (int r = 0; r < 4; ++r) {
                int row = row0 + wr + i * 16 + g * 4 + r;
                int col = col0 + wc + j * 16 + l15;
                C[(size_t)row * N + col] = (OutT)acc[i][j][r];
            }
}

__global__ __launch_bounds__(256) void gemm_qkv_kernel(const __bf16* __restrict__ xn,
                                                       const __bf16* __restrict__ wq,
                                                       const __bf16* __restrict__ wk,
                                                       const __bf16* __restrict__ wv,
                                                       __bf16* q, __bf16* k, __bf16* v) {
    int z = blockIdx.z;
    const __bf16* Bt = z == 0 ? wq : z == 1 ? wk : wv;
    __bf16* C = z == 0 ? q : z == 1 ? k : v;
    gemm_body<__bf16>(xn, Bt, C, DIM, DIM, (int)blockIdx.y << 7, (int)blockIdx.x << 7);
}

__global__ __launch_bounds__(256) void gemm_out_kernel(const __bf16* __restrict__ ctx,
                                                       const __bf16* __restrict__ wo,
                                                       float* __restrict__ out) {
    gemm_body<float>(ctx, wo, out, DIM, DIM, (int)blockIdx.y << 7, (int)blockIdx.x << 7);
}

// ---------------- MFMA causal flash attention, KVBLK=128 ----------------
__global__ __launch_bounds__(256) void attn_mfma_kernel(const __bf16* __restrict__ q,
                                                        const __bf16* __restrict__ k,
                                                        const __bf16* __restrict__ vt,
                                                        __bf16* __restrict__ ctx) {
    int bh = blockIdx.x;
    int qt = 31 - (int)blockIdx.y; // heavy tiles first
    int b = bh >> 4, h = bh & 15;
    int q0 = qt << 6;
    __shared__ __bf16 Ks[128][72];     // [s][d]
    __shared__ __bf16 Vl[64][136];     // [d][s_local]
    __shared__ __bf16 Ps[4][16][136];  // per-wave P
    int tid = threadIdx.x, w = tid >> 6, l = tid & 63, l15 = l & 15, g = l >> 4;
    size_t hoff = (size_t)(b * SEQ) * DIM + h * HD;
    const __bf16* vth = vt + (size_t)bh * HD * SEQ;

    // Q frags pre-scaled by 0.125*log2(e): QK^T lands directly in exp2 domain
    bf16x8 aq[2];
    {
        int qrow = q0 + w * 16 + l15;
        bf16x8 t0 = *(const bf16x8*)&q[hoff + (size_t)qrow * DIM + g * 8];
        bf16x8 t1 = *(const bf16x8*)&q[hoff + (size_t)qrow * DIM + 32 + g * 8];
        const float c2 = 0.125f * 1.44269504f;
#pragma unroll
        for (int j = 0; j < 8; ++j) {
            aq[0][j] = (__bf16)((float)t0[j] * c2);
            aq[1][j] = (__bf16)((float)t1[j] * c2);
        }
    }

    f32x4 acc_o[4];
#pragma unroll
    for (int j = 0; j < 4; ++j) acc_o[j] = f4zero();
    float m_run[4], l_run[4];
#pragma unroll
    for (int r = 0; r < 4; ++r) {
        m_run[r] = -1e30f;
        l_run[r] = 0.f;
    }

    int ksr = tid >> 3, kd0 = (tid & 7) * 8;  // K staging: row base, d offset
    int vdr = tid >> 4, vs0 = (tid & 15) * 8; // V staging: d base, s offset

    int nst = (q0 + 191) >> 7; // number of 128-wide KV tiles
    bf16x8 rk[4], rv[4];
#pragma unroll
    for (int c = 0; c < 4; ++c) {
        rk[c] = *(const bf16x8*)&k[hoff + (size_t)(c * 32 + ksr) * DIM + kd0];
        rv[c] = *(const bf16x8*)&vth[(size_t)(c * 16 + vdr) * SEQ + vs0];
    }

    for (int st = 0; st < nst; ++st) {
        int s0 = st << 7;
        __syncthreads();
#pragma unroll
        for (int c = 0; c < 4; ++c) {
            *(bf16x8*)&Ks[c * 32 + ksr][kd0] = rk[c];
            *(bf16x8*)&Vl[c * 16 + vdr][vs0] = rv[c];
        }
        __syncthreads();
        if (st + 1 < nst) {
            int sn = s0 + 128;
#pragma unroll
            for (int c = 0; c < 4; ++c) {
                rk[c] = *(const bf16x8*)&k[hoff + (size_t)(sn + c * 32 + ksr) * DIM + kd0];
                rv[c] = *(const bf16x8*)&vth[(size_t)(c * 16 + vdr) * SEQ + sn + vs0];
            }
        }

        // S (exp2 domain) = Qs @ K^T : 16 rows x 128 cols per wave
        f32x4 sacc[8];
#pragma unroll
        for (int j = 0; j < 8; ++j) sacc[j] = f4zero();
        __builtin_amdgcn_s_setprio(1);
#pragma unroll
        for (int j = 0; j < 8; ++j) {
            bf16x8 bk0 = *(const bf16x8*)&Ks[j * 16 + l15][g * 8];
            bf16x8 bk1 = *(const bf16x8*)&Ks[j * 16 + l15][32 + g * 8];
            sacc[j] = __builtin_amdgcn_mfma_f32_16x16x32_bf16(aq[0], bk0, sacc[j], 0, 0, 0);
            sacc[j] = __builtin_amdgcn_mfma_f32_16x16x32_bf16(aq[1], bk1, sacc[j], 0, 0, 0);
        }
        __builtin_amdgcn_s_setprio(0);

        if (st == nst - 1) { // causal mask (only the tile containing the diagonal)
#pragma unroll
            for (int j = 0; j < 8; ++j) {
                int scol = s0 + j * 16 + l15;
#pragma unroll
                for (int r = 0; r < 4; ++r) {
                    int rowq = q0 + w * 16 + g * 4 + r;
                    if (scol > rowq) sacc[j][r] = -1e30f;
                }
            }
        }

        // online softmax with defer-max (THR=11.0 in base-2 domain)
#pragma unroll
        for (int r = 0; r < 4; ++r) {
            float tl = sacc[0][r];
#pragma unroll
            for (int j = 1; j < 8; ++j) tl = fmaxf(tl, sacc[j][r]);
            if (!__all(tl <= m_run[r] + 11.0f)) {
#pragma unroll
                for (int off = 1; off < 16; off <<= 1) tl = fmaxf(tl, __shfl_xor(tl, off));
                float m_new = fmaxf(m_run[r], tl);
                float alpha = exp2f(m_run[r] - m_new);
                l_run[r] *= alpha;
#pragma unroll
                for (int jd = 0; jd < 4; ++jd) acc_o[jd][r] *= alpha;
                m_run[r] = m_new;
            }
            float rs = 0.f;
#pragma unroll
            for (int j = 0; j < 8; ++j) {
                float p = exp2f(sacc[j][r] - m_run[r]);
                Ps[w][g * 4 + r][j * 16 + l15] = (__bf16)p;
                rs += p;
            }
#pragma unroll
            for (int off = 1; off < 16; off <<= 1) rs += __shfl_xor(rs, off);
            l_run[r] += rs;
        }

        // acc_o += P @ V  (per-wave P buffer; in-wave DS ordering)
        bf16x8 ap[4];
#pragma unroll
        for (int ks = 0; ks < 4; ++ks) ap[ks] = *(const bf16x8*)&Ps[w][l15][ks * 32 + g * 8];
        __builtin_amdgcn_s_setprio(1);
#pragma unroll
        for (int jd = 0; jd < 4; ++jd)
#pragma unroll
            for (int ks = 0; ks < 4; ++ks) {
                bf16x8 bv = *(const bf16x8*)&Vl[jd * 16 + l15][ks * 32 + g * 8];
                acc_o[jd] = __builtin_amdgcn_mfma_f32_16x16x32_bf16(ap[ks], bv, acc_o[jd], 0, 0, 0);
            }
        __builtin_amdgcn_s_setprio(0);
    }

#pragma unroll
    for (int r = 0; r < 4; ++r) {
        float inv = 1.0f / l_run[r];
        int row = q0 + w * 16 + g * 4 + r;
#pragma unroll
        for (int jd = 0; jd < 4; ++jd)
            ctx[hoff + (size_t)row * DIM + jd * 16 + l15] = (__bf16)(acc_o[jd][r] * inv);
    }
}

extern "C" void kernel_launch(void* const* d_in, const int* in_sizes, int n_in,
                              void* d_out, int out_size, void* d_ws, size_t ws_size,
                              hipStream_t stream) {
    const float* x = (const float*)d_in[0];
    const float* w_norm = (const float*)d_in[1];
    const float* Wq = (const float*)d_in[2];
    const float* Wk = (const float*)d_in[3];
    const float* Wv = (const float*)d_in[4];
    const float* Wo = (const float*)d_in[5];
    float* out = (float*)d_out;
    char* w8 = (char*)d_ws;

    __bf16* xn = (__bf16*)(w8);                 // 8 MB
    __bf16* wtq = (__bf16*)(w8 + (8ull << 20)); // 2 MB each
    __bf16* wtk = (__bf16*)(w8 + (10ull << 20));
    __bf16* wtv = (__bf16*)(w8 + (12ull << 20));
    __bf16* wto = (__bf16*)(w8 + (14ull << 20));
    __bf16* qb = (__bf16*)(w8 + (16ull << 20)); // 8 MB each
    __bf16* kb = (__bf16*)(w8 + (24ull << 20));
    __bf16* vb = (__bf16*)(w8 + (32ull << 20));
    __bf16* vtb = (__bf16*)(w8 + (40ull << 20));
    __bf16* ctx = (__bf16*)(w8 + (48ull << 20));
    float* cosT = (float*)(w8 + (56ull << 20));
    float* sinT = cosT + SEQ * 32;

    wcvt_kernel<<<dim3(32, 32, 4), 256, 0, stream>>>(Wq, Wk, Wv, Wo, wtq, wtk, wtv, wto);
    rmsnorm_bf16<<<ROWS, 256, 0, stream>>>(x, w_norm, xn);
    rope_table_kernel<<<(SEQ * 32) / 256, 256, 0, stream>>>(cosT, sinT);

    gemm_qkv_kernel<<<dim3(DIM / 128, ROWS / 128, 3), 256, 0, stream>>>(xn, wtq, wtk, wtv, qb, kb, vb);

    rope_apply_bf16<<<dim3((ROWS * 64) / 256, 2), 256, 0, stream>>>(qb, kb, cosT, sinT);
    vtrans_kernel<<<dim3(SEQ / 32, HD / 32, BATCH * NHEADS), 256, 0, stream>>>(vb, vtb);

    attn_mfma_kernel<<<dim3(BATCH * NHEADS, SEQ / 64), 256, 0, stream>>>(qb, kb, vtb, ctx);

    gemm_out_kernel<<<dim3(DIM / 128, ROWS / 128), 256, 0, stream>>>(ctx, wto, out);
}